// Round 7
// baseline (187.228 us; speedup 1.0000x reference)
//
#include <hip/hip_runtime.h>

// Block-diagonal equivariant linear: 256x0e + 256x1o + 128x2e, B=32768, DIM=1664.
// ONE main kernel, segments interleaved across block IDs (all run concurrently).
// Per block: 8 consecutive tiles, software-pipelined:
//   DMA(t+1) via global_load_lds (fp32, linear, zero VGPR) issued BEFORE
//   compute(t); after compute: vmcnt(0)+barrier, deint pass (contiguous f32x4
//   LDS reads -> f2bf -> write-side (u,i) scatter to bf16 A-tile), barrier.
// MFMA reads b128 from bf16 tile; direct fp32 stores.

typedef short short8 __attribute__((ext_vector_type(8)));
typedef short short4v __attribute__((ext_vector_type(4)));
typedef float f32x4 __attribute__((ext_vector_type(4)));

#define DIMF 1664

__device__ __forceinline__ unsigned short f2bf(float f) {
  // round-to-nearest-even fp32 -> bf16 (finite gaussian inputs; no NaN path)
  unsigned int u = __float_as_uint(f);
  u += 0x7fffu + ((u >> 16) & 1u);
  return (unsigned short)(u >> 16);
}

__device__ __forceinline__ void gload16(const float* g, float* l) {
  // 16B global -> LDS direct (dest = wave-uniform base + lane*16)
  __builtin_amdgcn_global_load_lds(
      (const __attribute__((address_space(1))) void*)g,
      (__attribute__((address_space(3))) void*)l, 16, 0, 0);
}

// ws layout per segment: W[u][w] row-major; contraction over u (k), output col w (n).
// Fragment order: element ((ntg*NKS + ks)*64 + lane)*8 + j holds
//   W[k = ks*32 + (lane>>4)*8 + j][n = ntg*16 + (lane&15)] * scale  as bf16.
__global__ __launch_bounds__(256) void prep_w(const float* __restrict__ ws,
                                              unsigned short* __restrict__ wf) {
  int t = blockIdx.x * blockDim.x + threadIdx.x;  // group index, 8 bf16 per group
  int MUL, woff, goff;
  float scale;
  if (t < 8192) {
    MUL = 256; woff = 0; goff = 0; scale = 0.0625f;
  } else if (t < 16384) {
    MUL = 256; woff = 65536; goff = 8192; scale = 0.0625f;
  } else if (t < 18432) {
    MUL = 128; woff = 131072; goff = 16384; scale = 0.088388347648318447f;  // 1/sqrt(128)
  } else {
    return;
  }
  int g = t - goff;
  int l = g & 63;
  int nks = MUL >> 5;
  int ks = (g >> 6) % nks;
  int nt = g / (64 * nks);
  int n = nt * 16 + (l & 15);
  int kb = ks * 32 + (l >> 4) * 8;
  short8 v;
#pragma unroll
  for (int j = 0; j < 8; ++j)
    v[j] = (short)f2bf(ws[woff + (size_t)(kb + j) * MUL + n] * scale);
  *reinterpret_cast<short8*>(wf + (size_t)t * 8) = v;
}

// L: flat fp32 staging of one tile (BMB rows x SEGW floats), DMA'd linearly.
// Dd: bf16 A-tile [row = b*D+i][u], row stride LDA = MUL+8 (row byte stride
//     528/272 -> 16*odd -> b128 frag reads ~2-way = free).
template <int MUL, int D, int BMB, int TPB, int S, bool BIAS>
__device__ __forceinline__ void seg_run(const float* __restrict__ x,
                                        const unsigned short* __restrict__ wf,
                                        const float* __restrict__ bs,
                                        float* __restrict__ out, int tb, char* lds) {
  constexpr int SEGW = MUL * D;        // f32 per row (256 / 768 / 640)
  constexpr int LF = BMB * SEGW;       // L floats (8192 / 12288 / 10240)
  constexpr int NISS = LF / 256;       // 1KB DMA issues (32 / 48 / 40)
  constexpr int LDA = MUL + 8;
  constexpr int MT = BMB * D;          // A rows (32 / 48 / 80)
  constexpr int NMT = MT / 16;         // m-tiles (2 / 3 / 5)
  constexpr int NTW = MUL / 64;        // n-tiles per wave, 4 waves (4 / 4 / 2)
  constexpr int NKS = MUL / 32;        // k-steps (8 / 8 / 4)
  constexpr int NG4 = LF / 1024;       // deint f32x4 per thread (8 / 12 / 10)

  float* L = (float*)lds;
  unsigned short* Dd = (unsigned short*)(lds + LF * 4);

  const int tid = threadIdx.x;
  const int lane = tid & 63;
  const int wave = tid >> 6;
  const int l15 = lane & 15;
  const int lhi = lane >> 4;
  const int t0 = tb * TPB;

  float bias[NTW];
  if (BIAS) {
#pragma unroll
    for (int nt = 0; nt < NTW; ++nt) bias[nt] = bs[(wave * NTW + nt) * 16 + l15];
  }

  auto dma_tile = [&](int b0) {
#pragma unroll
    for (int m = wave; m < NISS; m += 4) {
      int q = m * 256 + lane * 4;     // f32 index in flat tile
      int r = q / SEGW;               // per-lane row (chunks may straddle rows)
      int c = q - r * SEGW;
      gload16(x + (size_t)(b0 + r) * DIMF + S + c, L + m * 256);
    }
  };

  auto deint = [&]() {
#pragma unroll
    for (int it = 0; it < NG4; ++it) {
      int g = tid + it * 256;
      f32x4 v = reinterpret_cast<const f32x4*>(L)[g];
      int q = g * 4;
      int r = q / SEGW;
      int c = q - r * SEGW;
      if (D == 1) {
        short4v p;
#pragma unroll
        for (int j = 0; j < 4; ++j) p[j] = (short)f2bf(v[j]);
        *reinterpret_cast<short4v*>(&Dd[r * LDA + c]) = p;
      } else {
#pragma unroll
        for (int j = 0; j < 4; ++j) {
          int col = c + j;
          int u = col / D;
          int i = col - u * D;
          Dd[(r * D + i) * LDA + u] = f2bf(v[j]);
        }
      }
    }
  };

  auto compute_store = [&](int b0) {
    f32x4 acc[NMT][NTW];
#pragma unroll
    for (int a = 0; a < NMT; ++a)
#pragma unroll
      for (int b = 0; b < NTW; ++b) acc[a][b] = (f32x4){0.f, 0.f, 0.f, 0.f};
#pragma unroll
    for (int ks = 0; ks < NKS; ++ks) {
      short8 af[NMT];
#pragma unroll
      for (int mt = 0; mt < NMT; ++mt)
        af[mt] = *reinterpret_cast<const short8*>(
            &Dd[(mt * 16 + l15) * LDA + ks * 32 + lhi * 8]);
#pragma unroll
      for (int nt = 0; nt < NTW; ++nt) {
        int ntg = wave * NTW + nt;
        short8 bfr = *reinterpret_cast<const short8*>(
            wf + ((size_t)(ntg * NKS + ks) * 64 + lane) * 8);
#pragma unroll
        for (int mt = 0; mt < NMT; ++mt)
          acc[mt][nt] = __builtin_amdgcn_mfma_f32_16x16x32_bf16(af[mt], bfr,
                                                                acc[mt][nt], 0, 0, 0);
      }
    }
    // C/D layout: col = lane&15, row = (lane>>4)*4 + q
#pragma unroll
    for (int nt = 0; nt < NTW; ++nt) {
      int n = wave * (MUL / 4) + nt * 16 + l15;
      float bi = BIAS ? bias[nt] : 0.f;
#pragma unroll
      for (int mt = 0; mt < NMT; ++mt)
#pragma unroll
        for (int q = 0; q < 4; ++q) {
          int m = mt * 16 + lhi * 4 + q;
          int b = m / D;
          int i = m - b * D;
          out[(size_t)(b0 + b) * DIMF + S + n * D + i] = acc[mt][nt][q] + bi;
        }
    }
  };

  // ---- prologue: stage + deint tile t0 ----
  dma_tile(t0 * BMB);
  asm volatile("s_waitcnt vmcnt(0)" ::: "memory");
  __syncthreads();
  deint();
  __syncthreads();

  // ---- pipelined loop: DMA(t+1) in flight during compute(t) ----
#pragma unroll 1
  for (int tt = 0; tt < TPB; ++tt) {
    if (tt + 1 < TPB) dma_tile((t0 + tt + 1) * BMB);  // into L (free after deint)
    compute_store((t0 + tt) * BMB);
    if (tt + 1 < TPB) {
      asm volatile("s_waitcnt vmcnt(0)" ::: "memory");
      __syncthreads();   // DMA landed AND all Dd reads done
      deint();           // L(t+1) -> Dd
      __syncthreads();   // Dd ready; L free for next DMA
    }
  }
}

__global__ __launch_bounds__(256, 2) void linear_main(
    const float* __restrict__ x, const unsigned short* __restrict__ wf,
    const float* __restrict__ bs, float* __restrict__ out) {
  // worst branch (seg1): L 48*1024B + Dd 48*264*2B = 49152 + 25344 = 74496 B
  __shared__ __align__(16) char lds[74496];
  int blk = blockIdx.x;
  int r = blk % 5;
  int g = blk / 5;
  if (r < 2) {
    seg_run<256, 3, 16, 8, 256, false>(x, wf + 65536, bs, out, g * 2 + r, lds);
  } else if (r < 4) {
    seg_run<128, 5, 16, 8, 1024, false>(x, wf + 131072, bs, out, g * 2 + (r - 2), lds);
  } else {
    seg_run<256, 1, 32, 8, 0, true>(x, wf, bs, out, g, lds);
  }
}

extern "C" void kernel_launch(void* const* d_in, const int* in_sizes, int n_in,
                              void* d_out, int out_size, void* d_ws, size_t ws_size,
                              hipStream_t stream) {
  const float* ws = (const float*)d_in[0];  // 147456
  const float* bs = (const float*)d_in[1];  // 256
  const float* x = (const float*)d_in[2];   // 32768 x 1664
  float* out = (float*)d_out;
  unsigned short* wf = (unsigned short*)d_ws;  // 147456 bf16 = 294912 B

  hipLaunchKernelGGL(prep_w, dim3(72), dim3(256), 0, stream, ws, wf);
  // 640 blocks: blk%5 -> {seg1,seg1,seg2,seg2,seg0}; per block 8 consecutive tiles.
  // seg0: 1024 tiles/8 = 128 blocks; seg1/seg2: 2048/8 = 256 blocks each.
  hipLaunchKernelGGL(linear_main, dim3(640), dim3(256), 0, stream, x, wf, bs, out);
}

// Round 8
// 136.535 us; speedup vs baseline: 1.3713x; 1.3713x over previous
//
#include <hip/hip_runtime.h>

// Block-diagonal equivariant linear: 256x0e + 256x1o + 128x2e, B=32768, DIM=1664.
// R2 mechanics, half-size tiles for 5-6 co-resident blocks/CU (statistical
// phase pipelining): VGPR-staged contiguous f32x4 loads (<=24 staged VGPR),
// write-side (u,i)-deinterleave to bf16 LDS, b128 A-frag reads,
// mfma_f32_16x16x32_bf16, direct fp32 stores. One barrier per block.
// Blocks ordered [seg0|seg1|seg2] consecutively (L3-friendly sweep).

typedef short short8 __attribute__((ext_vector_type(8)));
typedef short short4v __attribute__((ext_vector_type(4)));
typedef float f32x4 __attribute__((ext_vector_type(4)));

#define DIMF 1664

__device__ __forceinline__ unsigned short f2bf(float f) {
  // round-to-nearest-even fp32 -> bf16 (finite gaussian inputs; no NaN path)
  unsigned int u = __float_as_uint(f);
  u += 0x7fffu + ((u >> 16) & 1u);
  return (unsigned short)(u >> 16);
}

// ws layout per segment: W[u][w] row-major; contraction over u (k), output col w (n).
// Fragment order: element ((ntg*NKS + ks)*64 + lane)*8 + j holds
//   W[k = ks*32 + (lane>>4)*8 + j][n = ntg*16 + (lane&15)] * scale  as bf16.
__global__ __launch_bounds__(256) void prep_w(const float* __restrict__ ws,
                                              unsigned short* __restrict__ wf) {
  int t = blockIdx.x * blockDim.x + threadIdx.x;  // group index, 8 bf16 per group
  int MUL, woff, goff;
  float scale;
  if (t < 8192) {
    MUL = 256; woff = 0; goff = 0; scale = 0.0625f;
  } else if (t < 16384) {
    MUL = 256; woff = 65536; goff = 8192; scale = 0.0625f;
  } else if (t < 18432) {
    MUL = 128; woff = 131072; goff = 16384; scale = 0.088388347648318447f;  // 1/sqrt(128)
  } else {
    return;
  }
  int g = t - goff;
  int l = g & 63;
  int nks = MUL >> 5;
  int ks = (g >> 6) % nks;
  int nt = g / (64 * nks);
  int n = nt * 16 + (l & 15);
  int kb = ks * 32 + (l >> 4) * 8;
  short8 v;
#pragma unroll
  for (int j = 0; j < 8; ++j)
    v[j] = (short)f2bf(ws[woff + (size_t)(kb + j) * MUL + n] * scale);
  *reinterpret_cast<short8*>(wf + (size_t)t * 8) = v;
}

// LDS tile: A[row = b*D+i][u] bf16, row stride LDA = MUL+8 (row byte stride
// 528/272 = 16*odd -> b128 frag reads 2-way bank aliased = free).
// Rows padded to NMT*16; pad rows zeroed once (tail m-tiles partially garbage-
// free, stores masked anyway).
template <int MUL, int D, int BMB, bool BIAS>
__device__ __forceinline__ void seg_run(const float* __restrict__ x,
                                        const unsigned short* __restrict__ wf,
                                        const float* __restrict__ bs,
                                        float* __restrict__ out, int blk, int s,
                                        unsigned short* A) {
  constexpr int LDA = MUL + 8;
  constexpr int MT = BMB * D;              // valid A rows (16 / 24 / 40)
  constexpr int NMT = (MT + 15) / 16;      // m-tiles (1 / 2 / 3)
  constexpr int NTW = MUL / 64;            // n-tiles per wave, 4 waves (4 / 4 / 2)
  constexpr int NKS = MUL / 32;            // k-steps (8 / 8 / 4)
  constexpr int CPR = MUL * D / 4;         // f32x4 per batch row (64 / 192 / 160)
  constexpr int NG = BMB * CPR / 256;      // staged f32x4 per thread (4 / 6 / 5)
  constexpr int PADR = NMT * 16 - MT;      // pad rows (0 / 8 / 8)

  const int tid = threadIdx.x;
  const int lane = tid & 63;
  const int wave = tid >> 6;
  const int l15 = lane & 15;
  const int lhi = lane >> 4;
  const int b0 = blk * BMB;

  float bias[NTW];
  if (BIAS) {
#pragma unroll
    for (int nt = 0; nt < NTW; ++nt) bias[nt] = bs[(wave * NTW + nt) * 16 + l15];
  }

  // ---- load: all NG f32x4 in flight before any convert ----
  f32x4 v[NG];
#pragma unroll
  for (int it = 0; it < NG; ++it) {
    int g = tid + it * 256;
    int r = g / CPR;
    int c = (g - r * CPR) * 4;
    v[it] = *reinterpret_cast<const f32x4*>(x + (size_t)(b0 + r) * DIMF + s + c);
  }

  // zero pad rows (once; never written by deint)
  if (PADR > 0) {
    for (int z = tid; z < PADR * LDA / 4; z += 256)
      reinterpret_cast<unsigned long long*>(&A[MT * LDA])[z] = 0ull;
  }

  // ---- convert + write-side deinterleave ----
#pragma unroll
  for (int it = 0; it < NG; ++it) {
    int g = tid + it * 256;
    int r = g / CPR;
    int c = (g - r * CPR) * 4;
    if (D == 1) {
      short4v p;
#pragma unroll
      for (int j = 0; j < 4; ++j) p[j] = (short)f2bf(v[it][j]);
      *reinterpret_cast<short4v*>(&A[r * LDA + c]) = p;
    } else {
      int u0 = c / D;
      int i0 = c - u0 * D;
#pragma unroll
      for (int j = 0; j < 4; ++j) {
        int ii = i0 + j;  // wraps at most once for D in {3,5}, j<4
        int u = u0;
        if (ii >= D) { ii -= D; ++u; }
        A[(r * D + ii) * LDA + u] = f2bf(v[it][j]);
      }
    }
  }
  __syncthreads();  // the only barrier

  // ---- MFMA ----
  f32x4 acc[NMT][NTW];
#pragma unroll
  for (int a = 0; a < NMT; ++a)
#pragma unroll
    for (int b = 0; b < NTW; ++b) acc[a][b] = (f32x4){0.f, 0.f, 0.f, 0.f};
#pragma unroll
  for (int ks = 0; ks < NKS; ++ks) {
    short8 af[NMT];
#pragma unroll
    for (int mt = 0; mt < NMT; ++mt)
      af[mt] = *reinterpret_cast<const short8*>(
          &A[(mt * 16 + l15) * LDA + ks * 32 + lhi * 8]);
#pragma unroll
    for (int nt = 0; nt < NTW; ++nt) {
      int ntg = wave * NTW + nt;
      short8 bfr = *reinterpret_cast<const short8*>(
          wf + ((size_t)(ntg * NKS + ks) * 64 + lane) * 8);
#pragma unroll
      for (int mt = 0; mt < NMT; ++mt)
        acc[mt][nt] =
            __builtin_amdgcn_mfma_f32_16x16x32_bf16(af[mt], bfr, acc[mt][nt], 0, 0, 0);
    }
  }

  // ---- epilogue: C/D layout col = lane&15, row = (lane>>4)*4 + q ----
#pragma unroll
  for (int nt = 0; nt < NTW; ++nt) {
    int n = wave * (MUL / 4) + nt * 16 + l15;
    float bi = BIAS ? bias[nt] : 0.f;
#pragma unroll
    for (int mt = 0; mt < NMT; ++mt)
#pragma unroll
      for (int q = 0; q < 4; ++q) {
        int m = mt * 16 + lhi * 4 + q;
        if (MT % 16 != 0 && mt == NMT - 1 && m >= MT) continue;  // masked tail
        int b = m / D;
        int i = m - b * D;
        out[(size_t)(b0 + b) * DIMF + s + n * D + i] = acc[mt][nt][q] + bi;
      }
  }
}

__global__ __launch_bounds__(256) void linear_main(const float* __restrict__ x,
                                                   const unsigned short* __restrict__ wf,
                                                   const float* __restrict__ bs,
                                                   float* __restrict__ out) {
  // max: seg1 32 rows x 264 u16 = 16896 B
  __shared__ __align__(16) unsigned short A[32 * 264];
  int blk = blockIdx.x;
  if (blk < 2048) {
    seg_run<256, 1, 16, true>(x, wf, bs, out, blk, 0, A);
  } else if (blk < 6144) {
    seg_run<256, 3, 8, false>(x, wf + 65536, bs, out, blk - 2048, 256, A);
  } else {
    seg_run<128, 5, 8, false>(x, wf + 131072, bs, out, blk - 6144, 1024, A);
  }
}

extern "C" void kernel_launch(void* const* d_in, const int* in_sizes, int n_in,
                              void* d_out, int out_size, void* d_ws, size_t ws_size,
                              hipStream_t stream) {
  const float* ws = (const float*)d_in[0];  // 147456
  const float* bs = (const float*)d_in[1];  // 256
  const float* x = (const float*)d_in[2];   // 32768 x 1664
  float* out = (float*)d_out;
  unsigned short* wf = (unsigned short*)d_ws;  // 147456 bf16 = 294912 B

  hipLaunchKernelGGL(prep_w, dim3(72), dim3(256), 0, stream, ws, wf);
  // [seg0: 2048 | seg1: 4096 | seg2: 4096] blocks, consecutive batch sweep
  hipLaunchKernelGGL(linear_main, dim3(10240), dim3(256), 0, stream, x, wf, bs, out);
}